// Round 11
// baseline (376.752 us; speedup 1.0000x reference)
//
#include <hip/hip_runtime.h>
#include <math.h>

#define N_EMBD 512
#define N_HEAD 8
#define SEQ_T  2048
#define BATCH  4
#define QKV_LD 1536
#define NBLK   512

typedef __attribute__((ext_vector_type(8))) short bf16x8;  // 8 bf16 (4 VGPRs)
typedef __attribute__((ext_vector_type(4))) float f32x4;

#define CL 0.18033688f   // 0.125 * log2(e)

__device__ __forceinline__ unsigned short f2bf(float f) {
    union { float f; unsigned int u; } x; x.f = f;
    return (unsigned short)((x.u + 0x7FFFu + ((x.u >> 16) & 1u)) >> 16);  // RNE
}
__device__ __forceinline__ unsigned pack_trunc(float a, float b) {
    union { float f; unsigned u; } x, y; x.f = a; y.f = b;
    return __builtin_amdgcn_perm(y.u, x.u, 0x07060302u);
}
__device__ __forceinline__ bf16x8 scale_frag(bf16x8 v, float c) {
    bf16x8 r;
    #pragma unroll
    for (int i = 0; i < 8; ++i) {
        union { unsigned u; float f; } x;
        x.u = ((unsigned)(unsigned short)v[i]) << 16;
        r[i] = (short)f2bf(x.f * c);
    }
    return r;
}
__device__ __forceinline__ void gl_lds16(const void* g, void* s) {
    __builtin_amdgcn_global_load_lds(
        (const __attribute__((address_space(1))) void*)g,
        (__attribute__((address_space(3))) void*)s, 16, 0, 0);
}

// ---------------------------------------------------------------------------
// Shared-memory union across phases (max = attn, 50.4 KB; <= 80 KB @ 2/CU)
// ---------------------------------------------------------------------------
struct AttnSh { unsigned short Ks[2][4096], Vt[2][4096], PsA[4][1152], PsB[4][1152]; };
struct GemmSh { unsigned short As[4096], Bs[8192]; };          // 64x64 + 128x64
struct PrepSh { float t[32][33]; };
union SharedU { AttnSh a; GemmSh g; PrepSh p; };

// ---------------------------------------------------------------------------
// Device-scope grid barrier: all NBLK blocks are co-resident
// (__launch_bounds__(256,2) => >=2 blocks/CU; 512 = 256 CU x 2). ACQ_REL
// agent atomics flush/invalidate per-XCD L2 (G16 cross-XCD visibility).
// ---------------------------------------------------------------------------
__device__ __forceinline__ void grid_sync(int* bar) {
    __syncthreads();
    if (threadIdx.x == 0) {
        __hip_atomic_fetch_add(bar, 1, __ATOMIC_ACQ_REL, __HIP_MEMORY_SCOPE_AGENT);
        while (__hip_atomic_load(bar, __ATOMIC_ACQUIRE, __HIP_MEMORY_SCOPE_AGENT) < NBLK)
            __builtin_amdgcn_s_sleep(2);
    }
    __syncthreads();
}

// ---------------------------------------------------------------------------
// P0: weight transpose tile (job < 768: w1 [512][1536]; else w2 [512][512])
// ---------------------------------------------------------------------------
__device__ __forceinline__ void prep_tile(
    PrepSh& sp, int job,
    const float* __restrict__ w1, unsigned short* __restrict__ w1t,
    const float* __restrict__ w2, unsigned short* __restrict__ w2t, int tid)
{
    const float* W; unsigned short* Wt; int N, tt, nb;
    if (job < 768) { tt = job;       W = w1; Wt = w1t; N = 1536; nb = 48; }
    else           { tt = job - 768; W = w2; Wt = w2t; N = 512;  nb = 16; }
    const int n0 = (tt % nb) * 32, k0 = (tt / nb) * 32;
    const int tx = tid & 31, ty = tid >> 5;
    #pragma unroll
    for (int i = 0; i < 4; ++i)
        sp.t[ty + i * 8][tx] = W[(size_t)(k0 + ty + i * 8) * N + n0 + tx];
    __syncthreads();
    #pragma unroll
    for (int i = 0; i < 4; ++i)
        Wt[(size_t)(n0 + ty + i * 8) * 512 + k0 + tx] = f2bf(sp.t[tx][ty + i * 8]);
    __syncthreads();   // LDS reuse guard for the next job
}

// ---------------------------------------------------------------------------
// GEMM tile 64x128, K=512, BK=64 (R10-proven body, fixed shape).
// ---------------------------------------------------------------------------
template <bool CVT_A, bool BF16_OUT>
__device__ __forceinline__ void gemm_tile(
    GemmSh& sg, const void* __restrict__ Asrc,
    const unsigned short* __restrict__ Bt, const float* __restrict__ bias,
    void* __restrict__ C, int N, int row0, int col0, int tid)
{
    constexpr int K = 512;
    constexpr int WMT = 2, WNT = 4, SA = 2, SB = 4;
    const int wave = tid >> 6, lane = tid & 63;
    const int low  = lane & 15, quad = lane >> 4;
    const int wm   = (wave & 1) * 32, wn = (wave >> 1) * 64;

    size_t a_src[SA]; int a_dst[SA];
    #pragma unroll
    for (int s = 0; s < SA; ++s) {
        const int p = tid + 256 * s;
        const int m = p >> 3, q = p & 7;
        a_src[s] = (size_t)(row0 + m) * K + q * 8;
        a_dst[s] = m * 64 + (q ^ (m & 7)) * 8;
    }
    size_t b_src[SB]; int b_dst[SB];
    #pragma unroll
    for (int s = 0; s < SB; ++s) {
        const int p = tid + 256 * s;
        const int m = p >> 3, q = p & 7;
        b_src[s] = (size_t)(col0 + m) * K + q * 8;
        b_dst[s] = m * 64 + (q ^ (m & 7)) * 8;
    }

    f32x4 acc[WMT][WNT];
    #pragma unroll
    for (int i = 0; i < WMT; ++i)
        #pragma unroll
        for (int j = 0; j < WNT; ++j) acc[i][j] = (f32x4){0.f, 0.f, 0.f, 0.f};

    bf16x8 ar[SA], br[SB];
    const float*          af32 = (const float*)Asrc;
    const unsigned short* a16  = (const unsigned short*)Asrc;

    #pragma unroll
    for (int s = 0; s < SA; ++s) {
        if (CVT_A) {
            const float4 f0 = *(const float4*)(af32 + a_src[s]);
            const float4 f1 = *(const float4*)(af32 + a_src[s] + 4);
            union { uint4 v; bf16x8 h; } u;
            u.v.x = pack_trunc(f0.x, f0.y); u.v.y = pack_trunc(f0.z, f0.w);
            u.v.z = pack_trunc(f1.x, f1.y); u.v.w = pack_trunc(f1.z, f1.w);
            ar[s] = u.h;
        } else {
            ar[s] = *(const bf16x8*)(a16 + a_src[s]);
        }
    }
    #pragma unroll
    for (int s = 0; s < SB; ++s) br[s] = *(const bf16x8*)(Bt + b_src[s]);

    const int NIT = K >> 6;   // 8
    for (int it = 0; it < NIT; ++it) {
        __syncthreads();
        #pragma unroll
        for (int s = 0; s < SA; ++s) *(bf16x8*)&sg.As[a_dst[s]] = ar[s];
        #pragma unroll
        for (int s = 0; s < SB; ++s) *(bf16x8*)&sg.Bs[b_dst[s]] = br[s];
        __syncthreads();

        if (it + 1 < NIT) {
            const int ko = (it + 1) * 64;
            #pragma unroll
            for (int s = 0; s < SA; ++s) {
                if (CVT_A) {
                    const float4 f0 = *(const float4*)(af32 + a_src[s] + ko);
                    const float4 f1 = *(const float4*)(af32 + a_src[s] + ko + 4);
                    union { uint4 v; bf16x8 h; } u;
                    u.v.x = pack_trunc(f0.x, f0.y); u.v.y = pack_trunc(f0.z, f0.w);
                    u.v.z = pack_trunc(f1.x, f1.y); u.v.w = pack_trunc(f1.z, f1.w);
                    ar[s] = u.h;
                } else {
                    ar[s] = *(const bf16x8*)(a16 + a_src[s] + ko);
                }
            }
            #pragma unroll
            for (int s = 0; s < SB; ++s) br[s] = *(const bf16x8*)(Bt + b_src[s] + ko);
        }

        #pragma unroll
        for (int h = 0; h < 2; ++h) {
            bf16x8 af[WMT], bfr[WNT];
            #pragma unroll
            for (int t = 0; t < WMT; ++t)
                af[t] = *(const bf16x8*)
                    &sg.As[(wm + t * 16 + low) * 64 + (((h * 4 + quad) ^ (low & 7)) * 8)];
            #pragma unroll
            for (int t = 0; t < WNT; ++t)
                bfr[t] = *(const bf16x8*)
                    &sg.Bs[(wn + t * 16 + low) * 64 + (((h * 4 + quad) ^ (low & 7)) * 8)];
            #pragma unroll
            for (int i = 0; i < WMT; ++i)
                #pragma unroll
                for (int j = 0; j < WNT; ++j)
                    acc[i][j] = __builtin_amdgcn_mfma_f32_16x16x32_bf16(
                        af[i], bfr[j], acc[i][j], 0, 0, 0);
        }
    }
    __syncthreads();   // LDS reuse guard (next job's stores)

    float bv[WNT];
    #pragma unroll
    for (int j = 0; j < WNT; ++j) bv[j] = bias[col0 + wn + j * 16 + low];
    #pragma unroll
    for (int i = 0; i < WMT; ++i)
        #pragma unroll
        for (int r = 0; r < 4; ++r) {
            const size_t row = row0 + wm + i * 16 + quad * 4 + r;
            #pragma unroll
            for (int j = 0; j < WNT; ++j) {
                const int col = col0 + wn + j * 16 + low;
                const float v = acc[i][j][r] + bv[j];
                if (BF16_OUT)
                    ((unsigned short*)C)[row * N + col] = f2bf(v);
                else
                    ((float*)C)[row * N + col] = v;
            }
        }
}

// ---------------------------------------------------------------------------
// attention helpers (R9/R10-proven, verbatim math)
// ---------------------------------------------------------------------------
template <bool MASK>
__device__ __forceinline__ void tile_step(
    const bf16x8 kf[4][2], const bf16x8 qf0, const bf16x8 qf1,
    int thr, int quad, int low, unsigned short* ps)
{
    f32x4 s[4];
    #pragma unroll
    for (int st = 0; st < 4; ++st) {
        f32x4 a = (f32x4){0.f, 0.f, 0.f, 0.f};
        a = __builtin_amdgcn_mfma_f32_16x16x32_bf16(kf[st][0], qf0, a, 0, 0, 0);
        a = __builtin_amdgcn_mfma_f32_16x16x32_bf16(kf[st][1], qf1, a, 0, 0, 0);
        s[st] = a;
    }
    #pragma unroll
    for (int st = 0; st < 4; ++st) {
        float p[4];
        #pragma unroll
        for (int r = 0; r < 4; ++r) {
            float v = s[st][r];
            if (MASK) v = (st * 16 + r <= thr) ? v : -1e30f;
            p[r] = __builtin_amdgcn_exp2f(v);
        }
        uint2 pk;
        pk.x = pack_trunc(p[0], p[1]);
        pk.y = pack_trunc(p[2], p[3]);
        *(uint2*)&ps[low * 72 + st * 16 + quad * 4] = pk;
    }
}

__device__ __forceinline__ void pv_step(
    const bf16x8 vf[4][2], const unsigned short* ps, int quad, int low,
    f32x4* o, f32x4& lacc, const bf16x8 ones)
{
    const bf16x8 p0 = *(const bf16x8*)&ps[low * 72 + quad * 8];
    const bf16x8 p1 = *(const bf16x8*)&ps[low * 72 + quad * 8 + 32];
    #pragma unroll
    for (int t = 0; t < 4; ++t) {
        o[t] = __builtin_amdgcn_mfma_f32_16x16x32_bf16(p0, vf[t][0], o[t], 0, 0, 0);
        o[t] = __builtin_amdgcn_mfma_f32_16x16x32_bf16(p1, vf[t][1], o[t], 0, 0, 0);
    }
    lacc = __builtin_amdgcn_mfma_f32_16x16x32_bf16(p0, ones, lacc, 0, 0, 0);
    lacc = __builtin_amdgcn_mfma_f32_16x16x32_bf16(p1, ones, lacc, 0, 0, 0);
}

__device__ __forceinline__ void attn_block(
    AttnSh& sa, int id,
    const unsigned short* __restrict__ qkv, unsigned short* __restrict__ y, int tid)
{
    const int bh  = id & 31;                  // same-bh blocks -> same XCD
    const int pa  = id >> 5;                  // 0..15
    const int b   = bh >> 3, h = bh & 7;
    const int qA0 = pa * 64;
    const int qB0 = (31 - pa) * 64;
    const int nA  = pa + 1, nB = 32 - pa;
    const int wave = tid >> 6, lane = tid & 63;
    const int low  = lane & 15, quad = lane >> 4;

    const size_t base = (size_t)b * SEQ_T * QKV_LD + h * 64;
    const unsigned short* qp = qkv + base;
    const unsigned short* kp = qkv + base + 512;
    const unsigned short* vp = qkv + base + 1024;

    const int qmyA = qA0 + wave * 16 + low;
    const int qmyB = qB0 + wave * 16 + low;

    const bf16x8 qfA0 = scale_frag(*(const bf16x8*)(qp + (size_t)qmyA * QKV_LD + quad * 8), CL);
    const bf16x8 qfA1 = scale_frag(*(const bf16x8*)(qp + (size_t)qmyA * QKV_LD + quad * 8 + 32), CL);
    const bf16x8 qfB0 = scale_frag(*(const bf16x8*)(qp + (size_t)qmyB * QKV_LD + quad * 8), CL);
    const bf16x8 qfB1 = scale_frag(*(const bf16x8*)(qp + (size_t)qmyB * QKV_LD + quad * 8 + 32), CL);

    bf16x8 ones;
    #pragma unroll
    for (int i = 0; i < 8; ++i) ones[i] = (short)0x3F80;

    const int d0 = wave * 8;
    unsigned short* psA = &sa.PsA[wave][0];
    unsigned short* psB = &sa.PsB[wave][0];

    bf16x8 vr0 = *(const bf16x8*)(vp + (size_t)lane * QKV_LD + d0);
    bf16x8 vr1 = *(const bf16x8*)(vp + (size_t)lane * QKV_LD + d0 + 32);
    {
        #pragma unroll
        for (int ii = 0; ii < 2; ++ii) {
            const int row = wave * 16 + ii * 8 + (lane >> 3);
            const int o   = (lane & 7) ^ (lane >> 3);
            gl_lds16(kp + (size_t)row * QKV_LD + o * 8, &sa.Ks[0][(wave * 2 + ii) * 512]);
        }
        #pragma unroll
        for (int ii = 0; ii < 8; ++ii) {
            const int po = ((lane >> 3) ^ ii) * 8 + (lane & 7);
            sa.Vt[0][((d0 + ii) << 6) + po]      = (unsigned short)vr0[ii];
            sa.Vt[0][((d0 + 32 + ii) << 6) + po] = (unsigned short)vr1[ii];
        }
        if (nB > 1) {
            vr0 = *(const bf16x8*)(vp + (size_t)(64 + lane) * QKV_LD + d0);
            vr1 = *(const bf16x8*)(vp + (size_t)(64 + lane) * QKV_LD + d0 + 32);
        }
    }
    __syncthreads();

    f32x4 oA[4], oB[4], lA, lB;
    #pragma unroll
    for (int t = 0; t < 4; ++t) {
        oA[t] = (f32x4){0.f, 0.f, 0.f, 0.f};
        oB[t] = (f32x4){0.f, 0.f, 0.f, 0.f};
    }
    lA = (f32x4){0.f, 0.f, 0.f, 0.f};
    lB = (f32x4){0.f, 0.f, 0.f, 0.f};

    for (int kc = 0; kc < nB; ++kc) {
        const int cur = kc & 1;
        unsigned short* ksc = &sa.Ks[cur][0];
        unsigned short* vtc = &sa.Vt[cur][0];

        if (kc + 1 < nB) {
            const int key1 = (kc + 1) * 64;
            #pragma unroll
            for (int ii = 0; ii < 2; ++ii) {
                const int row = wave * 16 + ii * 8 + (lane >> 3);
                const int o   = (lane & 7) ^ (lane >> 3);
                gl_lds16(kp + (size_t)(key1 + row) * QKV_LD + o * 8,
                         &sa.Ks[cur ^ 1][(wave * 2 + ii) * 512]);
            }
            unsigned short* vtn = &sa.Vt[cur ^ 1][0];
            #pragma unroll
            for (int ii = 0; ii < 8; ++ii) {
                const int po = ((lane >> 3) ^ ii) * 8 + (lane & 7);
                vtn[((d0 + ii) << 6) + po]      = (unsigned short)vr0[ii];
                vtn[((d0 + 32 + ii) << 6) + po] = (unsigned short)vr1[ii];
            }
        }
        if (kc + 2 < nB) {
            const int key2 = (kc + 2) * 64;
            vr0 = *(const bf16x8*)(vp + (size_t)(key2 + lane) * QKV_LD + d0);
            vr1 = *(const bf16x8*)(vp + (size_t)(key2 + lane) * QKV_LD + d0 + 32);
        }

        const int key0 = kc * 64;
        bf16x8 kf[4][2];
        #pragma unroll
        for (int t = 0; t < 4; ++t)
            #pragma unroll
            for (int i = 0; i < 2; ++i)
                kf[t][i] = *(const bf16x8*)
                    &ksc[((t * 16 + low) << 6) + (((quad + 4 * i) ^ (low & 7)) << 3)];

        if (kc < nA) {
            if (kc == nA - 1)
                tile_step<true >(kf, qfA0, qfA1, qmyA - key0 - quad * 4, quad, low, psA);
            else
                tile_step<false>(kf, qfA0, qfA1, 0, quad, low, psA);
        }
        if (kc == nB - 1)
            tile_step<true >(kf, qfB0, qfB1, qmyB - key0 - quad * 4, quad, low, psB);
        else
            tile_step<false>(kf, qfB0, qfB1, 0, quad, low, psB);

        asm volatile("" ::: "memory");

        bf16x8 vf[4][2];
        #pragma unroll
        for (int t = 0; t < 4; ++t)
            #pragma unroll
            for (int i = 0; i < 2; ++i)
                vf[t][i] = *(const bf16x8*)
                    &vtc[((t * 16 + low) << 6) + (((quad + 4 * i) ^ (low & 7)) << 3)];

        if (kc < nA) pv_step(vf, psA, quad, low, oA, lA, ones);
        pv_step(vf, psB, quad, low, oB, lB, ones);
        __syncthreads();
    }

    #pragma unroll
    for (int r = 0; r < 4; ++r) {
        const float rlA = 1.f / lA[r];
        const int qrow = qA0 + wave * 16 + quad * 4 + r;
        unsigned short* yp = y + (size_t)(b * SEQ_T + qrow) * N_EMBD + h * 64 + low;
        #pragma unroll
        for (int t = 0; t < 4; ++t) yp[16 * t] = f2bf(oA[t][r] * rlA);
    }
    #pragma unroll
    for (int r = 0; r < 4; ++r) {
        const float rlB = 1.f / lB[r];
        const int qrow = qB0 + wave * 16 + quad * 4 + r;
        unsigned short* yp = y + (size_t)(b * SEQ_T + qrow) * N_EMBD + h * 64 + low;
        #pragma unroll
        for (int t = 0; t < 4; ++t) yp[16 * t] = f2bf(oB[t][r] * rlB);
    }
}

// ---------------------------------------------------------------------------
// MEGA kernel: P0 prep -> P1 gemm1 -> P2 attn -> P3 gemm2, grid barriers
// between phases. 512 blocks, all co-resident (launch_bounds(256,2)).
// ---------------------------------------------------------------------------
__global__ __launch_bounds__(256, 2) void mega(
    const float* __restrict__ x,
    const float* __restrict__ w1, const float* __restrict__ b1,
    const float* __restrict__ w2, const float* __restrict__ b2,
    float* __restrict__ out,
    unsigned short* __restrict__ qkv, unsigned short* __restrict__ ybf,
    unsigned short* __restrict__ w1t, unsigned short* __restrict__ w2t,
    int* __restrict__ bars)
{
    __shared__ SharedU sh;
    const int id  = blockIdx.x;
    const int tid = threadIdx.x;

    // ---- P0: weight transposes (1024 jobs, 2 per block) ----
    prep_tile(sh.p, id,       w1, w1t, w2, w2t, tid);
    prep_tile(sh.p, id + 512, w1, w1t, w2, w2t, tid);
    grid_sync(&bars[0]);

    // ---- P1: gemm1 qkv = x @ w1t^T + b1 (1536 jobs, 3 per block, XCD-local)
    #pragma unroll
    for (int j = 0; j < 3; ++j) {
        const int job    = id + NBLK * j;
        const int xcd    = job & 7;
        const int within = job >> 3;              // 0..191
        const int row0   = (xcd * 16 + (within & 15)) * 64;
        const int col0   = (within >> 4) * 128;
        gemm_tile<true, true>(sh.g, x, w1t, b1, qkv, QKV_LD, row0, col0, tid);
    }
    grid_sync(&bars[1]);

    // ---- P2: attention (1 job per block) ----
    attn_block(sh.a, id, qkv, ybf, tid);
    grid_sync(&bars[2]);

    // ---- P3: gemm2 out = y @ w2t^T + b2 (512 jobs, 1 per block, XCD-local)
    {
        const int xcd    = id & 7;
        const int within = id >> 3;               // 0..63
        const int row0   = (xcd * 16 + (within & 15)) * 64;
        const int col0   = (within >> 4) * 128;
        gemm_tile<false, false>(sh.g, ybf, w2t, b2, out, N_EMBD, row0, col0, tid);
    }
}

// ---------------------------------------------------------------------------
extern "C" void kernel_launch(void* const* d_in, const int* in_sizes, int n_in,
                              void* d_out, int out_size, void* d_ws, size_t ws_size,
                              hipStream_t stream)
{
    const float* x      = (const float*)d_in[0];
    const float* attn_w = (const float*)d_in[1];   // [512][1536]
    const float* attn_b = (const float*)d_in[2];
    const float* proj_w = (const float*)d_in[3];   // [512][512]
    const float* proj_b = (const float*)d_in[4];
    float*       out    = (float*)d_out;

    char* ws = (char*)d_ws;
    unsigned short* qkv_bf = (unsigned short*)(ws);                      // 25.2 MB
    unsigned short* y_bf   = (unsigned short*)(ws + 25165824);           //  8.4 MB
    unsigned short* w1t    = (unsigned short*)(ws + 33554432);           //  1.6 MB
    unsigned short* w2t    = (unsigned short*)(ws + 35127296);           //  0.5 MB
    int*            bars   = (int*)(ws + 35651584);                      //  barrier ctr

    hipMemsetAsync(bars, 0, 64, stream);

    mega<<<dim3(NBLK), 256, 0, stream>>>(
        x, attn_w, attn_b, proj_w, proj_b, out,
        qkv_bf, y_bf, w1t, w2t, bars);
}